// Round 5
// baseline (35.474 us; speedup 1.0000x reference)
//
#include <hip/hip_runtime.h>

#define B_SIZE 16384
#define DIM    128
#define NCLS   100
#define NSEG   128
#define SEGSZ  128
#define TS     32
#define MAXTILES 131329
#define PAIR_GRID 512

// ---------------- workspace layout (int units) ----------------
#define WS_SEGBASE 0                        // NCLS*NSEG = 12800
#define WS_NORMS   12800                    // 16384 floats (sorted order)
#define WS_NTILES  (WS_NORMS + 16384)       // 1 (+3 pad)
#define WS_PARTIAL (WS_NTILES + 4)          // 512
#define WS_TILES   (WS_PARTIAL + 512 + 4)   // int2 x MAXTILES (even offset -> 8B aligned)
#define WS_XS      (WS_TILES + 2 * MAXTILES + 2)  // bf16 16384x128, 16B-aligned byte offset

typedef short bf8 __attribute__((ext_vector_type(8)));
typedef float f32x4 __attribute__((ext_vector_type(4)));

__device__ __forceinline__ unsigned bf16_rne(float f) {
    unsigned u = __float_as_uint(f);
    return (u + 0x7FFFu + ((u >> 16) & 1u)) >> 16;
}

// 1) single-block plan: seg-hist (LDS), class offsets, per-segment bases, tile list
__global__ __launch_bounds__(1024) void plan_kernel(const int* __restrict__ target,
                                                    int* __restrict__ seg_base,
                                                    int2* __restrict__ tiles,
                                                    int* __restrict__ ntiles) {
    __shared__ int sh[NSEG * NCLS];          // [g*NCLS + c]
    __shared__ int tot[NCLS], cls_off[NCLS + 1], tile_off[NCLS + 1];
    const int tid = threadIdx.x;
    for (int i = tid; i < NSEG * NCLS; i += 1024) sh[i] = 0;
    __syncthreads();
    for (int i = tid; i < B_SIZE; i += 1024)
        atomicAdd(&sh[(i >> 7) * NCLS + target[i]], 1);
    __syncthreads();
    if (tid < NCLS) {
        int s = 0;
        for (int g = 0; g < NSEG; ++g) s += sh[g * NCLS + tid];
        tot[tid] = s;
    }
    __syncthreads();
    if (tid == 0) {
        int a = 0;
        for (int k = 0; k < NCLS; ++k) { cls_off[k] = a; a += tot[k]; }
        cls_off[NCLS] = a;
    }
    __syncthreads();
    if (tid < NCLS) {
        int a = cls_off[tid];
        for (int g = 0; g < NSEG; ++g) {
            seg_base[tid * NSEG + g] = a;
            a += sh[g * NCLS + tid];
        }
        int T = (tot[tid] + TS - 1) / TS;
        tot[tid] = T * (T + 1) / 2;          // reuse as per-class tile count
    }
    __syncthreads();
    if (tid == 0) {
        int a = 0;
        for (int k = 0; k < NCLS; ++k) { tile_off[k] = a; a += tot[k]; }
        *ntiles = a;
    }
    __syncthreads();
    if (tid < NCLS) {
        const int beg = cls_off[tid], end = cls_off[tid + 1];
        const int T = (end - beg + TS - 1) / TS;
        int o = tile_off[tid];
        const int w0 = (int)((unsigned)beg | ((unsigned)end << 16));
        for (int ti = 0; ti < T; ++ti)
            for (int tj = ti; tj < T; ++tj, ++o)
                tiles[o] = make_int2(w0, ti | (tj << 12));
    }
}

// 2) fused: stable in-segment rank + gather-convert to sorted bf16 + norms
__global__ __launch_bounds__(256) void scatter_gather_kernel(
        const float* __restrict__ x, const int* __restrict__ target,
        const int* __restrict__ seg_base,
        unsigned short* __restrict__ xs, float* __restrict__ normS) {
    __shared__ int tloc[SEGSZ];
    __shared__ int posb[SEGSZ];
    __shared__ int base_s[NCLS];
    const int seg = blockIdx.x;
    const int t = threadIdx.x;
    if (t < SEGSZ) tloc[t] = target[seg * SEGSZ + t];
    if (t < NCLS) base_s[t] = seg_base[t * NSEG + seg];
    __syncthreads();
    if (t < SEGSZ) {
        const int c = tloc[t];
        int r = 0;
        for (int j = 0; j < t; ++j) r += (tloc[j] == c);
        posb[t] = base_s[c] + r;
    }
    __syncthreads();

    const int ch = t & 15;           // 16 lanes per row
    #pragma unroll
    for (int it = 0; it < 8; ++it) {
        const int row = it * 16 + (t >> 4);
        const int pos = posb[row];
        const float4* src = reinterpret_cast<const float4*>(
            x + ((size_t)seg * SEGSZ + row) * DIM + ch * 8);
        const float4 v0 = src[0], v1 = src[1];

        unsigned b0 = bf16_rne(v0.x), b1 = bf16_rne(v0.y),
                 b2 = bf16_rne(v0.z), b3 = bf16_rne(v0.w);
        unsigned b4 = bf16_rne(v1.x), b5 = bf16_rne(v1.y),
                 b6 = bf16_rne(v1.z), b7 = bf16_rne(v1.w);
        uint4 o;
        o.x = b0 | (b1 << 16); o.y = b2 | (b3 << 16);
        o.z = b4 | (b5 << 16); o.w = b6 | (b7 << 16);
        reinterpret_cast<uint4*>(xs + (size_t)pos * DIM + ch * 8)[0] = o;

        float c0 = __uint_as_float(b0 << 16), c1 = __uint_as_float(b1 << 16);
        float c2 = __uint_as_float(b2 << 16), c3 = __uint_as_float(b3 << 16);
        float c4 = __uint_as_float(b4 << 16), c5 = __uint_as_float(b5 << 16);
        float c6 = __uint_as_float(b6 << 16), c7 = __uint_as_float(b7 << 16);
        float s = c0*c0 + c1*c1 + c2*c2 + c3*c3 + c4*c4 + c5*c5 + c6*c6 + c7*c7;
        #pragma unroll
        for (int off = 1; off < 16; off <<= 1) s += __shfl_xor(s, off, 64);
        if (ch == 0) normS[pos] = s;
    }
}

// 3) MFMA pair kernel: one wave per 32x32 tile, contiguous sorted rows, no fences
__global__ __launch_bounds__(256) void pair_kernel(const unsigned short* __restrict__ xs,
                                                   const float* __restrict__ normS,
                                                   const int2* __restrict__ tiles,
                                                   const int* __restrict__ ntiles_p,
                                                   float* __restrict__ partials) {
    const int lane = threadIdx.x & 63;
    const int r16  = lane & 15;
    const int kl   = lane >> 4;
    const int gwave  = blockIdx.x * 4 + (threadIdx.x >> 6);
    const int nwaves = gridDim.x * 4;
    const int nt = *ntiles_p;

    float acc = 0.0f;

    for (int t = gwave; t < nt; t += nwaves) {
        const int2 tw = tiles[t];
        const int beg = tw.x & 0xFFFF;
        const int end = (int)(((unsigned)tw.x) >> 16);
        const int ti  = tw.y & 0xFFF;
        const int tj  = tw.y >> 12;
        const int pbase = beg + ti * TS;
        const int qbase = beg + tj * TS;
        const int last = end - 1;

        const int pa0 = min(pbase + r16, last),      pa1 = min(pbase + 16 + r16, last);
        const int qa0 = min(qbase + r16, last),      qa1 = min(qbase + 16 + r16, last);

        const bf8* rA0 = reinterpret_cast<const bf8*>(xs + (size_t)pa0 * DIM) + kl;
        const bf8* rA1 = reinterpret_cast<const bf8*>(xs + (size_t)pa1 * DIM) + kl;
        const bf8* rB0 = reinterpret_cast<const bf8*>(xs + (size_t)qa0 * DIM) + kl;
        const bf8* rB1 = reinterpret_cast<const bf8*>(xs + (size_t)qa1 * DIM) + kl;

        f32x4 c00 = {0.f, 0.f, 0.f, 0.f};
        f32x4 c01 = {0.f, 0.f, 0.f, 0.f};
        f32x4 c10 = {0.f, 0.f, 0.f, 0.f};
        f32x4 c11 = {0.f, 0.f, 0.f, 0.f};
        #pragma unroll
        for (int ks = 0; ks < 4; ++ks) {
            const bf8 a0 = rA0[ks * 4];
            const bf8 a1 = rA1[ks * 4];
            const bf8 b0 = rB0[ks * 4];
            const bf8 b1 = rB1[ks * 4];
            c00 = __builtin_amdgcn_mfma_f32_16x16x32_bf16(a0, b0, c00, 0, 0, 0);
            c01 = __builtin_amdgcn_mfma_f32_16x16x32_bf16(a0, b1, c01, 0, 0, 0);
            c10 = __builtin_amdgcn_mfma_f32_16x16x32_bf16(a1, b0, c10, 0, 0, 0);
            c11 = __builtin_amdgcn_mfma_f32_16x16x32_bf16(a1, b1, c11, 0, 0, 0);
        }

        const float nb0 = normS[qa0];
        const float nb1 = normS[qa1];
        float na[8];
        #pragma unroll
        for (int rg = 0; rg < 2; ++rg)
            #pragma unroll
            for (int r = 0; r < 4; ++r)
                na[rg * 4 + r] = normS[min(pbase + rg * 16 + kl * 4 + r, last)];

        const bool diag = (ti == tj);
        #pragma unroll
        for (int sub = 0; sub < 4; ++sub) {
            const int rg = sub >> 1, cg = sub & 1;
            const f32x4 cc = (sub == 0) ? c00 : (sub == 1) ? c01 : (sub == 2) ? c10 : c11;
            const int qcol = cg * 16 + r16;
            const int qq = qbase + qcol;
            const float nb = cg ? nb1 : nb0;
            #pragma unroll
            for (int r = 0; r < 4; ++r) {
                const int prow = rg * 16 + kl * 4 + r;
                const int pp = pbase + prow;
                const bool valid = (pp < end) && (qq < end) && (!diag || (prow < qcol));
                if (valid) {
                    const float d2 = na[rg * 4 + r] + nb - 2.0f * cc[r];
                    acc += sqrtf(fmaxf(d2, 0.0f));
                }
            }
        }
    }

    __shared__ float red[256];
    red[threadIdx.x] = acc;
    __syncthreads();
    for (int s = 128; s > 0; s >>= 1) {
        if (threadIdx.x < s) red[threadIdx.x] += red[threadIdx.x + s];
        __syncthreads();
    }
    if (threadIdx.x == 0) partials[blockIdx.x] = red[0];
}

// 4) single-wave final reduce (fixed order -> deterministic)
__global__ void reduce_kernel(const float* __restrict__ partials, float* __restrict__ out) {
    const int lane = threadIdx.x;
    float a = 0.0f;
    for (int i = lane; i < PAIR_GRID; i += 64) a += partials[i];
    #pragma unroll
    for (int off = 1; off < 64; off <<= 1) a += __shfl_xor(a, off, 64);
    if (lane == 0) out[0] = a / (float)B_SIZE;
}

extern "C" void kernel_launch(void* const* d_in, const int* in_sizes, int n_in,
                              void* d_out, int out_size, void* d_ws, size_t ws_size,
                              hipStream_t stream) {
    const float* x      = (const float*)d_in[0];
    const int*   target = (const int*)d_in[1];
    float*       out    = (float*)d_out;
    int*         ws     = (int*)d_ws;

    int*   seg_base = ws + WS_SEGBASE;
    float* normS    = (float*)(ws + WS_NORMS);
    int*   ntiles   = ws + WS_NTILES;
    float* partials = (float*)(ws + WS_PARTIAL);
    int2*  tiles    = (int2*)(ws + WS_TILES);
    unsigned short* xs = (unsigned short*)(ws + WS_XS);

    plan_kernel<<<1, 1024, 0, stream>>>(target, seg_base, tiles, ntiles);
    scatter_gather_kernel<<<NSEG, 256, 0, stream>>>(x, target, seg_base, xs, normS);
    pair_kernel<<<PAIR_GRID, 256, 0, stream>>>(xs, normS, tiles, ntiles, partials);
    reduce_kernel<<<1, 64, 0, stream>>>(partials, out);
}